// Round 3
// baseline (622.830 us; speedup 1.0000x reference)
//
#include <hip/hip_runtime.h>

#define HWDIM 1024             // 32*32
#define DDIM 256
#define KCODES 1024
#define NROWS 32768            // 32 * 1024
#define BSTRIDE (DDIM * HWDIM) // per-batch stride in input = 262144

// ---- ws layout (float units unless noted) ----
// wT    : [0, 262144)           transposed codebook, d-major [256][1024]
// rr    : [262144, 294912)      ||x_n||^2, numpy-pairwise fp32
// ss    : [294912, 295936)      ||e_k||^2, numpy-pairwise fp32
// gbest : [295936, 361472)      packed (ordered_dist<<32 | k) u64 per row
// hist  : [361472, 362496)      code histogram (int32)
// loss  : byte offset 1449984   (double)

// ---- out layout (floats) ----
// [0] loss ; [1, 8388609) quantized_st ; [8388609] perplexity ;
// [8388610, 41943042) encodings one-hot

// numpy-exact pairwise sum of squares over 128 elements (np pairwise block)
__device__ __forceinline__ float pair128_sq(const float* __restrict__ p, int stride) {
  float a[8];
#pragma unroll
  for (int j = 0; j < 8; ++j) { float v = p[j * stride]; a[j] = __fmul_rn(v, v); }
  for (int i = 8; i < 128; i += 8) {
#pragma unroll
    for (int j = 0; j < 8; ++j) {
      float v = p[(i + j) * stride];
      a[j] = __fadd_rn(a[j], __fmul_rn(v, v));
    }
  }
  float s01 = __fadd_rn(a[0], a[1]), s23 = __fadd_rn(a[2], a[3]);
  float s45 = __fadd_rn(a[4], a[5]), s67 = __fadd_rn(a[6], a[7]);
  return __fadd_rn(__fadd_rn(s01, s23), __fadd_rn(s45, s67));
}

// fused prep: transpose codebook, init gbest/hist/loss, codebook norms
__global__ void k_prep(const float* __restrict__ w, float* __restrict__ wT,
                       float* __restrict__ ss, unsigned long long* __restrict__ gbest,
                       int* __restrict__ hist, double* __restrict__ loss) {
  int g = blockIdx.x * 256 + threadIdx.x;   // 262144 threads
  {
    int k = g & 1023, d = g >> 10;
    wT[g] = w[k * DDIM + d];
  }
  if (g < NROWS) gbest[g] = 0xFFFFFFFFFFFFFFFFull;
  if (g < KCODES) {
    hist[g] = 0;
    const float* p = w + g * DDIM;
    ss[g] = __fadd_rn(pair128_sq(p, 1), pair128_sq(p + 128, 1));
  }
  if (g == 0) *loss = 0.0;
}

// ||x_n||^2 — row n reads input with stride HWDIM (coalesced across lanes)
__global__ void k_rownorm(const float* __restrict__ in, float* __restrict__ rr) {
  int n = blockIdx.x * blockDim.x + threadIdx.x;
  if (n >= NROWS) return;
  const float* p = in + (n >> 10) * BSTRIDE + (n & 1023);
  rr[n] = __fadd_rn(pair128_sq(p, HWDIM), pair128_sq(p + 128 * HWDIM, HWDIM));
}

// main distance + argmin: 128 rows x 256 codes per block, 8x16 micro-tile.
// Thread (R=t>>4, C=t&15): rows {R*4+i, 64+R*4+i}, codes {g*64 + C*4+j},
// all LDS reads <=2-way bank conflicts (free on gfx950).
#define DCHUNK 32
__global__ __launch_bounds__(256) void k_argmin(
    const float* __restrict__ in, const float* __restrict__ wT,
    const float* __restrict__ rr, const float* __restrict__ ss,
    unsigned long long* __restrict__ gbest) {
  __shared__ __align__(16) float xs[DCHUNK][128];   // 16 KB
  __shared__ __align__(16) float wsh[DCHUNK][256];  // 32 KB
  __shared__ unsigned long long best[128];          // 1 KB

  const int t = threadIdx.x;
  const int n0 = blockIdx.x * 128;    // 128-aligned -> same batch (1024 rows/batch)
  const int kc = blockIdx.y * 256;
  const float* xbase = in + (n0 >> 10) * BSTRIDE + (n0 & 1023);
  const int R = t >> 4, C = t & 15;

  if (t < 128) best[t] = 0xFFFFFFFFFFFFFFFFull;

  float acc[8][16];
#pragma unroll
  for (int i = 0; i < 8; ++i)
#pragma unroll
    for (int j = 0; j < 16; ++j) acc[i][j] = 0.f;

  for (int dc = 0; dc < DDIM; dc += DCHUNK) {
    __syncthreads();
#pragma unroll
    for (int m = 0; m < 4; ++m) {
      int u = t + m * 256;            // float4 index, 1024 total
      int d = u >> 5, c4 = u & 31;    // 32 float4 per d-row
      *(float4*)&xs[d][c4 * 4] =
          *(const float4*)(xbase + (dc + d) * HWDIM + c4 * 4);
    }
#pragma unroll
    for (int m = 0; m < 8; ++m) {
      int u = t + m * 256;            // float4 index, 2048 total
      int d = u >> 6, c4 = u & 63;    // 64 float4 per d-row
      *(float4*)&wsh[d][c4 * 4] =
          *(const float4*)(wT + (dc + d) * KCODES + kc + c4 * 4);
    }
    __syncthreads();
#pragma unroll 4
    for (int d = 0; d < DCHUNK; ++d) {
      float4 x0 = *(const float4*)&xs[d][R * 4];
      float4 x1 = *(const float4*)&xs[d][64 + R * 4];
      float4 w0 = *(const float4*)&wsh[d][C * 4];
      float4 w1 = *(const float4*)&wsh[d][64 + C * 4];
      float4 w2 = *(const float4*)&wsh[d][128 + C * 4];
      float4 w3 = *(const float4*)&wsh[d][192 + C * 4];
      float xa[8] = {x0.x, x0.y, x0.z, x0.w, x1.x, x1.y, x1.z, x1.w};
      float wa[16] = {w0.x, w0.y, w0.z, w0.w, w1.x, w1.y, w1.z, w1.w,
                      w2.x, w2.y, w2.z, w2.w, w3.x, w3.y, w3.z, w3.w};
#pragma unroll
      for (int i = 0; i < 8; ++i)
#pragma unroll
        for (int j = 0; j < 16; ++j) acc[i][j] = fmaf(xa[i], wa[j], acc[i][j]);
    }
  }

  // fold distances: dist = fl(fl(r+s) - 2m), numpy-exact (2m exact)
  float rv[8], sv[16];
#pragma unroll
  for (int i = 0; i < 4; ++i) {
    rv[i] = rr[n0 + R * 4 + i];
    rv[4 + i] = rr[n0 + 64 + R * 4 + i];
  }
#pragma unroll
  for (int j = 0; j < 16; ++j)
    sv[j] = ss[kc + (j >> 2) * 64 + C * 4 + (j & 3)];
#pragma unroll
  for (int i = 0; i < 8; ++i) {
    float bd = 3.402823466e+38f;
    int bk = 0;
#pragma unroll
    for (int j = 0; j < 16; ++j) {  // j ascending => global k ascending (tie->low k)
      float dist = fmaf(-2.0f, acc[i][j], __fadd_rn(rv[i], sv[j]));
      if (dist < bd) { bd = dist; bk = j; }
    }
    int kloc = kc + (bk >> 2) * 64 + C * 4 + (bk & 3);
    unsigned ub = __float_as_uint(bd);
    ub = (ub & 0x80000000u) ? ~ub : (ub | 0x80000000u);  // monotone map
    unsigned long long key = ((unsigned long long)ub << 32) | (unsigned)kloc;
    int row = (i < 4) ? (R * 4 + i) : (64 + R * 4 + (i - 4));
    atomicMin(&best[row], key);
  }

  __syncthreads();
  if (t < 128) atomicMin(&gbest[n0 + t], best[t]);
}

// one-hot encodings write (including zeros) + histogram. 4 rows per block.
__global__ void k_enc(const unsigned long long* __restrict__ gbest,
                      float2* __restrict__ enc, int* __restrict__ hist) {
  __shared__ unsigned kk[4];
  const int t = threadIdx.x;
  const int r0 = blockIdx.x * 4;
  if (t < 4) {
    unsigned k = (unsigned)(gbest[r0 + t] & 0xFFFFFFFFull);
    kk[t] = k;
    atomicAdd(&hist[k], 1);
  }
  __syncthreads();
#pragma unroll
  for (int m = 0; m < 8; ++m) {
    int u = t + m * 256;            // float2 index, 2048 total (4 rows x 512)
    int r = u >> 9, c2 = u & 511;
    int k = (int)kk[r];
    float2 v;
    v.x = (c2 * 2 == k) ? 1.0f : 0.0f;
    v.y = (c2 * 2 + 1 == k) ? 1.0f : 0.0f;
    enc[(size_t)(r0 + r) * 512 + c2] = v;
  }
}

// quantized_st + squared-error sum. Block = 64 rows (one hw-slice) x 256 d.
// Codebook rows staged through LDS in 64-d chunks -> all global traffic coalesced.
__global__ __launch_bounds__(256) void k_quant(
    const float* __restrict__ in, const float* __restrict__ w,
    const unsigned long long* __restrict__ gbest,
    float* __restrict__ outq, double* __restrict__ loss) {
  __shared__ float wrow[64][65];    // +1 pad: compute reads are 2-way (free)
  __shared__ unsigned kk[64];
  __shared__ double red[256];
  const int t = threadIdx.x;
  const int n0 = blockIdx.x * 64;   // 512 blocks
  const int b = n0 >> 10, hw0 = n0 & 1023;
  const float* inb = in + b * BSTRIDE + hw0;
  float* outb = outq + b * BSTRIDE + hw0;

  if (t < 64) kk[t] = (unsigned)(gbest[n0 + t] & 0xFFFFFFFFull);

  const int hwl = t & 63, dl = t >> 6;
  double lsum = 0.0;
  for (int dc = 0; dc < DDIM; dc += 64) {
    __syncthreads();                 // kk ready / previous chunk consumed
#pragma unroll
    for (int m = 0; m < 16; ++m) {
      int u = t + m * 256;           // 4096 elements: 64 rows x 64 d
      int r = u >> 6, dd = u & 63;
      wrow[r][dd] = w[kk[r] * DDIM + dc + dd];
    }
    __syncthreads();
#pragma unroll
    for (int dd = 0; dd < 64; dd += 4) {
      int d = dc + dd + dl;
      float x = inb[d * HWDIM + hwl];
      float wv = wrow[hwl][dd + dl];
      float diff = __fsub_rn(wv, x);               // fl(quantized - x)
      outb[d * HWDIM + hwl] = __fadd_rn(x, diff);  // fl(x + fl(q - x)) == np
      lsum += (double)diff * (double)diff;
    }
  }
  red[t] = lsum;
  __syncthreads();
  for (int s = 128; s > 0; s >>= 1) {
    if (t < s) red[t] += red[t + s];
    __syncthreads();
  }
  if (t == 0) atomicAdd(loss, red[0]);
}

__global__ void k_final(const int* __restrict__ hist, const double* __restrict__ loss,
                        float* __restrict__ out) {
  __shared__ double red[256];
  int t = threadIdx.x;
  double s = 0.0;
  for (int i = t; i < KCODES; i += 256) {
    double p = (double)hist[i] * (1.0 / 32768.0);
    s += p * log(p + 1e-10);
  }
  red[t] = s;
  __syncthreads();
  for (int st = 128; st > 0; st >>= 1) {
    if (t < st) red[t] += red[t + st];
    __syncthreads();
  }
  if (t == 0) {
    out[8388609] = (float)exp(-red[0]);
    double m = *loss / 8388608.0;
    out[0] = (float)(1.25 * m);   // q_latent + 0.25 * e_latent, identical values
  }
}

extern "C" void kernel_launch(void* const* d_in, const int* in_sizes, int n_in,
                              void* d_out, int out_size, void* d_ws, size_t ws_size,
                              hipStream_t stream) {
  const float* in = (const float*)d_in[0];   // [32,256,32,32]
  const float* w  = (const float*)d_in[1];   // [1024,256]
  float* out = (float*)d_out;

  float* wsf = (float*)d_ws;
  float* wT  = wsf;
  float* rr  = wsf + 262144;
  float* ssp = wsf + 294912;
  unsigned long long* gbest = (unsigned long long*)(wsf + 295936);
  int* hist = (int*)(wsf + 361472);
  double* loss = (double*)((char*)d_ws + 1449984);

  k_prep<<<dim3(1024), dim3(256), 0, stream>>>(w, wT, ssp, gbest, hist, loss);
  k_rownorm<<<dim3(128), dim3(256), 0, stream>>>(in, rr);
  k_argmin<<<dim3(256, 4), dim3(256), 0, stream>>>(in, wT, rr, ssp, gbest);
  k_enc<<<dim3(8192), dim3(256), 0, stream>>>(gbest, (float2*)(out + 8388610), hist);
  k_quant<<<dim3(512), dim3(256), 0, stream>>>(in, w, gbest, out + 1, loss);
  k_final<<<dim3(1), dim3(256), 0, stream>>>(hist, loss, out);
}

// Round 4
// 484.659 us; speedup vs baseline: 1.2851x; 1.2851x over previous
//
#include <hip/hip_runtime.h>

#define HWDIM 1024             // 32*32
#define DDIM 256
#define KCODES 1024
#define NROWS 32768            // 32 * 1024
#define BSTRIDE (DDIM * HWDIM) // per-batch stride in input = 262144

// ---- ws layout (float units unless noted) ----
// wT    : [0, 262144)           transposed codebook, d-major [256][1024]
// rr    : [262144, 294912)      ||x_n||^2, numpy-pairwise fp32
// ss    : [294912, 295936)      ||e_k||^2, numpy-pairwise fp32
// gbest : [295936, 361472)      packed (ordered_dist<<32 | k) u64 per row
// hist  : [361472, 362496)      code histogram (int32)
// loss  : byte offset 1449984   (double)

// ---- out layout (floats) ----
// [0] loss ; [1, 8388609) quantized_st ; [8388609] perplexity ;
// [8388610, 41943042) encodings one-hot

// numpy-exact pairwise sum of squares over 128 elements (np pairwise block)
__device__ __forceinline__ float pair128_sq(const float* __restrict__ p, int stride) {
  float a[8];
#pragma unroll
  for (int j = 0; j < 8; ++j) { float v = p[j * stride]; a[j] = __fmul_rn(v, v); }
  for (int i = 8; i < 128; i += 8) {
#pragma unroll
    for (int j = 0; j < 8; ++j) {
      float v = p[(i + j) * stride];
      a[j] = __fadd_rn(a[j], __fmul_rn(v, v));
    }
  }
  float s01 = __fadd_rn(a[0], a[1]), s23 = __fadd_rn(a[2], a[3]);
  float s45 = __fadd_rn(a[4], a[5]), s67 = __fadd_rn(a[6], a[7]);
  return __fadd_rn(__fadd_rn(s01, s23), __fadd_rn(s45, s67));
}

// prep: init gbest/hist/loss, codebook norms (32768 threads)
__global__ void k_prep(const float* __restrict__ w, float* __restrict__ ss,
                       unsigned long long* __restrict__ gbest,
                       int* __restrict__ hist, double* __restrict__ loss) {
  int g = blockIdx.x * 256 + threadIdx.x;
  gbest[g] = 0xFFFFFFFFFFFFFFFFull;
  if (g < KCODES) {
    hist[g] = 0;
    const float* p = w + g * DDIM;
    ss[g] = __fadd_rn(pair128_sq(p, 1), pair128_sq(p + 128, 1));
  }
  if (g == 0) *loss = 0.0;
}

// LDS-tiled transpose: w[k][d] -> wT[d][k], 64x64 tiles, both sides coalesced
__global__ void k_transpose(const float* __restrict__ w, float* __restrict__ wT) {
  __shared__ float tile[64][65];
  const int t = threadIdx.x;
  const int k0 = (blockIdx.x & 15) * 64, d0 = (blockIdx.x >> 4) * 64;
  const int c = t & 63, r = t >> 6;
#pragma unroll
  for (int m = 0; m < 16; ++m)
    tile[r + m * 4][c] = w[(k0 + r + m * 4) * DDIM + d0 + c];
  __syncthreads();
#pragma unroll
  for (int m = 0; m < 16; ++m)
    wT[(size_t)(d0 + r + m * 4) * KCODES + k0 + c] = tile[c][r + m * 4];
}

// ||x_n||^2 — row n reads input with stride HWDIM (coalesced across lanes)
__global__ void k_rownorm(const float* __restrict__ in, float* __restrict__ rr) {
  int n = blockIdx.x * blockDim.x + threadIdx.x;
  if (n >= NROWS) return;
  const float* p = in + (n >> 10) * BSTRIDE + (n & 1023);
  rr[n] = __fadd_rn(pair128_sq(p, HWDIM), pair128_sq(p + 128 * HWDIM, HWDIM));
}

// main distance + argmin: 128 rows x 128 codes per block, 8x8 micro-tile.
// Staging via global_load_lds width=16: each wave-instruction fills 2 contiguous
// 512B d-rows (LDS dest = wave-uniform base + lane*16 — layout unpadded).
#define DCHUNK 16
__global__ __launch_bounds__(256) void k_argmin(
    const float* __restrict__ in, const float* __restrict__ wT,
    const float* __restrict__ rr, const float* __restrict__ ss,
    unsigned long long* __restrict__ gbest) {
  __shared__ __align__(16) float xs[DCHUNK][128];   // 8 KB
  __shared__ __align__(16) float wsh[DCHUNK][128];  // 8 KB
  __shared__ unsigned long long best[128];          // 1 KB

  const int t = threadIdx.x;
  const int n0 = blockIdx.x * 128;    // 128-aligned -> same batch (1024 rows/batch)
  const int kc = blockIdx.y * 128;
  const float* xbase = in + (n0 >> 10) * BSTRIDE + (n0 & 1023);
  const int R = t >> 4, C = t & 15;

  // staging geometry: wave wv covers d-rows wv*4 .. wv*4+3 (two instrs of 2 rows)
  const int wv = t >> 6, ln = t & 63;
  const int srow = wv * 4;
  const int sr = srow + (ln >> 5);          // this lane's d-row within chunk (m=0)
  const int scol = (ln & 31) * 4;
  const float* xg = xbase + (size_t)sr * HWDIM + scol;
  const float* wg = wT + (size_t)sr * KCODES + kc + scol;

  if (t < 128) best[t] = 0xFFFFFFFFFFFFFFFFull;

  float acc[8][8];
#pragma unroll
  for (int i = 0; i < 8; ++i)
#pragma unroll
    for (int j = 0; j < 8; ++j) acc[i][j] = 0.f;

  for (int dc = 0; dc < DDIM; dc += DCHUNK) {
    __syncthreads();                        // previous chunk fully consumed
#pragma unroll
    for (int m = 0; m < 2; ++m) {
      __builtin_amdgcn_global_load_lds(
          (const __attribute__((address_space(1))) void*)(xg + (size_t)(dc + 2 * m) * HWDIM),
          (__attribute__((address_space(3))) void*)&xs[srow + 2 * m][0], 16, 0, 0);
      __builtin_amdgcn_global_load_lds(
          (const __attribute__((address_space(1))) void*)(wg + (size_t)(dc + 2 * m) * KCODES),
          (__attribute__((address_space(3))) void*)&wsh[srow + 2 * m][0], 16, 0, 0);
    }
    __syncthreads();                        // drains vmcnt -> staged data visible
#pragma unroll 8
    for (int d = 0; d < DCHUNK; ++d) {
      float4 x0 = *(const float4*)&xs[d][R * 4];
      float4 x1 = *(const float4*)&xs[d][64 + R * 4];
      float4 w0 = *(const float4*)&wsh[d][C * 4];
      float4 w1 = *(const float4*)&wsh[d][64 + C * 4];
      float xa[8] = {x0.x, x0.y, x0.z, x0.w, x1.x, x1.y, x1.z, x1.w};
      float wa[8] = {w0.x, w0.y, w0.z, w0.w, w1.x, w1.y, w1.z, w1.w};
#pragma unroll
      for (int i = 0; i < 8; ++i)
#pragma unroll
        for (int j = 0; j < 8; ++j) acc[i][j] = fmaf(xa[i], wa[j], acc[i][j]);
    }
  }

  // fold distances: dist = fl(fl(r+s) - 2m), numpy-exact (2m exact)
  float rv[8], sv[8];
#pragma unroll
  for (int i = 0; i < 4; ++i) {
    rv[i] = rr[n0 + R * 4 + i];
    rv[4 + i] = rr[n0 + 64 + R * 4 + i];
    sv[i] = ss[kc + C * 4 + i];
    sv[4 + i] = ss[kc + 64 + C * 4 + i];
  }
#pragma unroll
  for (int i = 0; i < 8; ++i) {
    float bd = 3.402823466e+38f;
    int bk = 0;
#pragma unroll
    for (int j = 0; j < 8; ++j) {   // j ascending => global k ascending (tie->low k)
      float dist = fmaf(-2.0f, acc[i][j], __fadd_rn(rv[i], sv[j]));
      if (dist < bd) { bd = dist; bk = j; }
    }
    int kloc = kc + ((bk < 4) ? (C * 4 + bk) : (64 + C * 4 + (bk - 4)));
    unsigned ub = __float_as_uint(bd);
    ub = (ub & 0x80000000u) ? ~ub : (ub | 0x80000000u);  // monotone map
    unsigned long long key = ((unsigned long long)ub << 32) | (unsigned)kloc;
    int row = (i < 4) ? (R * 4 + i) : (64 + R * 4 + (i - 4));
    atomicMin(&best[row], key);
  }

  __syncthreads();
  if (t < 128) atomicMin(&gbest[n0 + t], best[t]);
}

// one-hot encodings write (including zeros) + histogram. 4 rows per block.
__global__ void k_enc(const unsigned long long* __restrict__ gbest,
                      float2* __restrict__ enc, int* __restrict__ hist) {
  __shared__ unsigned kk[4];
  const int t = threadIdx.x;
  const int r0 = blockIdx.x * 4;
  if (t < 4) {
    unsigned k = (unsigned)(gbest[r0 + t] & 0xFFFFFFFFull);
    kk[t] = k;
    atomicAdd(&hist[k], 1);
  }
  __syncthreads();
#pragma unroll
  for (int m = 0; m < 8; ++m) {
    int u = t + m * 256;            // float2 index, 2048 total (4 rows x 512)
    int r = u >> 9, c2 = u & 511;
    int k = (int)kk[r];
    float2 v;
    v.x = (c2 * 2 == k) ? 1.0f : 0.0f;
    v.y = (c2 * 2 + 1 == k) ? 1.0f : 0.0f;
    enc[(size_t)(r0 + r) * 512 + c2] = v;
  }
}

// quantized_st + squared-error sum. Block = 64 rows (one hw-slice) x 256 d.
// Codebook rows staged through LDS in 64-d chunks -> all global traffic coalesced.
__global__ __launch_bounds__(256) void k_quant(
    const float* __restrict__ in, const float* __restrict__ w,
    const unsigned long long* __restrict__ gbest,
    float* __restrict__ outq, double* __restrict__ loss) {
  __shared__ float wrow[64][65];    // +1 pad: compute reads are 2-way (free)
  __shared__ unsigned kk[64];
  __shared__ double red[256];
  const int t = threadIdx.x;
  const int n0 = blockIdx.x * 64;   // 512 blocks
  const int b = n0 >> 10, hw0 = n0 & 1023;
  const float* inb = in + b * BSTRIDE + hw0;
  float* outb = outq + b * BSTRIDE + hw0;

  if (t < 64) kk[t] = (unsigned)(gbest[n0 + t] & 0xFFFFFFFFull);

  const int hwl = t & 63, dl = t >> 6;
  double lsum = 0.0;
  for (int dc = 0; dc < DDIM; dc += 64) {
    __syncthreads();                 // kk ready / previous chunk consumed
#pragma unroll
    for (int m = 0; m < 16; ++m) {
      int u = t + m * 256;           // 4096 elements: 64 rows x 64 d
      int r = u >> 6, dd = u & 63;
      wrow[r][dd] = w[kk[r] * DDIM + dc + dd];
    }
    __syncthreads();
#pragma unroll
    for (int dd = 0; dd < 64; dd += 4) {
      int d = dc + dd + dl;
      float x = inb[d * HWDIM + hwl];
      float wv = wrow[hwl][dd + dl];
      float diff = __fsub_rn(wv, x);               // fl(quantized - x)
      outb[d * HWDIM + hwl] = __fadd_rn(x, diff);  // fl(x + fl(q - x)) == np
      lsum += (double)diff * (double)diff;
    }
  }
  red[t] = lsum;
  __syncthreads();
  for (int s = 128; s > 0; s >>= 1) {
    if (t < s) red[t] += red[t + s];
    __syncthreads();
  }
  if (t == 0) atomicAdd(loss, red[0]);
}

__global__ void k_final(const int* __restrict__ hist, const double* __restrict__ loss,
                        float* __restrict__ out) {
  __shared__ double red[256];
  int t = threadIdx.x;
  double s = 0.0;
  for (int i = t; i < KCODES; i += 256) {
    double p = (double)hist[i] * (1.0 / 32768.0);
    s += p * log(p + 1e-10);
  }
  red[t] = s;
  __syncthreads();
  for (int st = 128; st > 0; st >>= 1) {
    if (t < st) red[t] += red[t + st];
    __syncthreads();
  }
  if (t == 0) {
    out[8388609] = (float)exp(-red[0]);
    double m = *loss / 8388608.0;
    out[0] = (float)(1.25 * m);   // q_latent + 0.25 * e_latent, identical values
  }
}

extern "C" void kernel_launch(void* const* d_in, const int* in_sizes, int n_in,
                              void* d_out, int out_size, void* d_ws, size_t ws_size,
                              hipStream_t stream) {
  const float* in = (const float*)d_in[0];   // [32,256,32,32]
  const float* w  = (const float*)d_in[1];   // [1024,256]
  float* out = (float*)d_out;

  float* wsf = (float*)d_ws;
  float* wT  = wsf;
  float* rr  = wsf + 262144;
  float* ssp = wsf + 294912;
  unsigned long long* gbest = (unsigned long long*)(wsf + 295936);
  int* hist = (int*)(wsf + 361472);
  double* loss = (double*)((char*)d_ws + 1449984);

  k_prep<<<dim3(128), dim3(256), 0, stream>>>(w, ssp, gbest, hist, loss);
  k_transpose<<<dim3(64), dim3(256), 0, stream>>>(w, wT);
  k_rownorm<<<dim3(128), dim3(256), 0, stream>>>(in, rr);
  k_argmin<<<dim3(256, 8), dim3(256), 0, stream>>>(in, wT, rr, ssp, gbest);
  k_enc<<<dim3(8192), dim3(256), 0, stream>>>(gbest, (float2*)(out + 8388610), hist);
  k_quant<<<dim3(512), dim3(256), 0, stream>>>(in, w, gbest, out + 1, loss);
  k_final<<<dim3(1), dim3(256), 0, stream>>>(hist, loss, out);
}

// Round 5
// 481.015 us; speedup vs baseline: 1.2948x; 1.0076x over previous
//
#include <hip/hip_runtime.h>
#include <hip/hip_bf16.h>

#define HWDIM 1024             // 32*32
#define DDIM 256
#define KCODES 1024
#define NROWS 32768            // 32 * 1024
#define BSTRIDE (DDIM * HWDIM) // per-batch stride in input = 262144
#define GUARD 1.5e-4f          // certification gap: > 2B_split + 4 half-ulps(256)

typedef __attribute__((ext_vector_type(8))) short short8;
typedef __attribute__((ext_vector_type(4))) float f32x4;
typedef unsigned long long ull;

// ---- ws byte layout ----
// wT      @0        (1048576)   fp32 codebook transposed [256][1024] (fallback)
// ss      @1048576  (4096)      ||e_k||^2 numpy-pairwise
// gbest   @1052672  (262144)    final packed (ordered_dist<<32|k) per row
// hist    @1314816  (4096)
// flags   @1318912  (131072)
// flagcnt @1449984  (4)
// loss    @1449992  (8)
// ---- scratch inside d_out encodings region (overwritten later by k_enc) ----
// base ob = (char*)d_out + 33554448 (16-aligned)
// xh8 @0, xl8 @16777216, gb8 @33554432, gs8 @35651584, wh8 @37748736, wl8 @38273024

__device__ __forceinline__ unsigned short f2bf(float v) {
  __hip_bfloat16 b = __float2bfloat16(v);
  return *reinterpret_cast<unsigned short*>(&b);
}
__device__ __forceinline__ float bf2f(unsigned short u) {
  __hip_bfloat16 b;
  *reinterpret_cast<unsigned short*>(&b) = u;
  return __bfloat162float(b);
}
__device__ __forceinline__ ull pk(float d, int k) {
  unsigned ub = __float_as_uint(d);
  ub = (ub & 0x80000000u) ? ~ub : (ub | 0x80000000u);  // monotone total order
  return ((ull)ub << 32) | (unsigned)k;
}
__device__ __forceinline__ float keyq(ull key) {
  unsigned ub = (unsigned)(key >> 32);
  unsigned orig = (ub & 0x80000000u) ? (ub & 0x7FFFFFFFu) : ~ub;
  return __uint_as_float(orig);
}

// numpy-exact pairwise sum of squares over 128 elements
__device__ __forceinline__ float pair128_sq(const float* p, int stride) {
  float a[8];
#pragma unroll
  for (int j = 0; j < 8; ++j) { float v = p[j * stride]; a[j] = __fmul_rn(v, v); }
  for (int i = 8; i < 128; i += 8) {
#pragma unroll
    for (int j = 0; j < 8; ++j) {
      float v = p[(i + j) * stride];
      a[j] = __fadd_rn(a[j], __fmul_rn(v, v));
    }
  }
  float s01 = __fadd_rn(a[0], a[1]), s23 = __fadd_rn(a[2], a[3]);
  float s45 = __fadd_rn(a[4], a[5]), s67 = __fadd_rn(a[6], a[7]);
  return __fadd_rn(__fadd_rn(s01, s23), __fadd_rn(s45, s67));
}

// prep: codebook bf16 hi/lo split into [oct][k][8] layout + ss + init
__global__ void k_prep(const float* __restrict__ w, float* __restrict__ ss,
                       int* __restrict__ hist, int* __restrict__ flagcnt,
                       double* __restrict__ loss,
                       unsigned short* __restrict__ wh8, unsigned short* __restrict__ wl8) {
  int g = blockIdx.x * 256 + threadIdx.x;  // 32768 = 1024 k x 32 octets
  {
    int k = g >> 5, oct = g & 31;
    const float* p = w + k * DDIM + oct * 8;
    short8 hv, lv;
#pragma unroll
    for (int j = 0; j < 8; ++j) {
      float v = p[j];
      unsigned short h = f2bf(v);
      unsigned short l = f2bf(__fsub_rn(v, bf2f(h)));
      hv[j] = (short)h; lv[j] = (short)l;
    }
    *(short8*)&wh8[oct * 8192 + k * 8] = hv;
    *(short8*)&wl8[oct * 8192 + k * 8] = lv;
  }
  if (g < KCODES) {
    hist[g] = 0;
    const float* p = w + g * DDIM;
    ss[g] = __fadd_rn(pair128_sq(p, 1), pair128_sq(p + 128, 1));
  }
  if (g == 0) { *flagcnt = 0; *loss = 0.0; }
}

// LDS-tiled transpose: w[k][d] -> wT[d][k] (fp32, for exact fallback)
__global__ void k_transpose(const float* __restrict__ w, float* __restrict__ wT) {
  __shared__ float tile[64][65];
  const int t = threadIdx.x;
  const int k0 = (blockIdx.x & 15) * 64, d0 = (blockIdx.x >> 4) * 64;
  const int c = t & 63, r = t >> 6;
#pragma unroll
  for (int m = 0; m < 16; ++m)
    tile[r + m * 4][c] = w[(k0 + r + m * 4) * DDIM + d0 + c];
  __syncthreads();
#pragma unroll
  for (int m = 0; m < 16; ++m)
    wT[(size_t)(d0 + r + m * 4) * KCODES + k0 + c] = tile[c][r + m * 4];
}

// input -> bf16 hi/lo split, transposed to [oct][n][8] (coalesced both sides)
__global__ __launch_bounds__(256) void k_split(const float* __restrict__ in,
                                               unsigned short* __restrict__ xh8,
                                               unsigned short* __restrict__ xl8) {
  __shared__ float tile[64][65];
  const int t = threadIdx.x;
  const int b = blockIdx.x >> 4, hw0 = (blockIdx.x & 15) * 64;
  const int lane = t & 63, grp = t >> 6;
  const float* inb = in + b * BSTRIDE + hw0;
  const int n = b * 1024 + hw0 + lane;
  for (int dc = 0; dc < 256; dc += 64) {
    __syncthreads();
#pragma unroll
    for (int m = 0; m < 16; ++m) {
      int dd = grp * 16 + m;
      tile[dd][lane] = inb[(dc + dd) * HWDIM + lane];
    }
    __syncthreads();
#pragma unroll
    for (int oo = 0; oo < 2; ++oo) {
      int ol = grp * 2 + oo;
      int oct = (dc >> 3) + ol;
      short8 hv, lv;
#pragma unroll
      for (int j = 0; j < 8; ++j) {
        float v = tile[ol * 8 + j][lane];
        unsigned short h = f2bf(v);
        unsigned short l = f2bf(__fsub_rn(v, bf2f(h)));
        hv[j] = (short)h; lv[j] = (short)l;
      }
      *(short8*)&xh8[(size_t)oct * 262144 + n * 8] = hv;
      *(short8*)&xl8[(size_t)oct * 262144 + n * 8] = lv;
    }
  }
}

#define GLL(gp, lp) __builtin_amdgcn_global_load_lds( \
    (const __attribute__((address_space(1))) void*)(gp), \
    (__attribute__((address_space(3))) void*)(lp), 16, 0, 0)

// MFMA distance-argmin: 128 rows x 128 codes per block, 3 bf16 MFMAs per k-step
// (xh*wh + xh*wl + xl*wh). Writes per-codeblock best & 2nd-best keys.
__global__ __launch_bounds__(256) void k_mfma(
    const unsigned short* __restrict__ xh8, const unsigned short* __restrict__ xl8,
    const unsigned short* __restrict__ wh8, const unsigned short* __restrict__ wl8,
    const float* __restrict__ ss, ull* __restrict__ gb8, ull* __restrict__ gs8) {
  __shared__ __align__(16) unsigned short Ah[128 * 32], Al[128 * 32];
  __shared__ __align__(16) unsigned short Bh[128 * 32], Bl[128 * 32];
  __shared__ ull best1[128], best2[128];
  const int t = threadIdx.x, wv = t >> 6, ln = t & 63;
  const int n0 = blockIdx.x * 128, kc = blockIdx.y * 128;
  if (t < 128) { best1[t] = ~0ull; best2[t] = ~0ull; }

  f32x4 acc[4][4];
#pragma unroll
  for (int i = 0; i < 4; ++i)
#pragma unroll
    for (int j = 0; j < 4; ++j) acc[i][j] = (f32x4){0.f, 0.f, 0.f, 0.f};

  const int lrow = ln >> 2, loct = ln & 3;       // staging: 16 rows x 4 octets/instr
  const int rb = (wv & 1) * 64, cb = (wv >> 1) * 64;
  const int q8 = (ln >> 4) * 8, l15 = ln & 15;

  for (int ki = 0; ki < 8; ++ki) {
    __syncthreads();
    const size_t ob = (size_t)(ki * 4 + loct);
    const int r0 = wv * 32;
    GLL(xh8 + ob * 262144 + (n0 + r0 + lrow) * 8,      &Ah[(r0) * 32]);
    GLL(xh8 + ob * 262144 + (n0 + r0 + 16 + lrow) * 8, &Ah[(r0 + 16) * 32]);
    GLL(xl8 + ob * 262144 + (n0 + r0 + lrow) * 8,      &Al[(r0) * 32]);
    GLL(xl8 + ob * 262144 + (n0 + r0 + 16 + lrow) * 8, &Al[(r0 + 16) * 32]);
    GLL(wh8 + ob * 8192 + (kc + r0 + lrow) * 8,        &Bh[(r0) * 32]);
    GLL(wh8 + ob * 8192 + (kc + r0 + 16 + lrow) * 8,   &Bh[(r0 + 16) * 32]);
    GLL(wl8 + ob * 8192 + (kc + r0 + lrow) * 8,        &Bl[(r0) * 32]);
    GLL(wl8 + ob * 8192 + (kc + r0 + 16 + lrow) * 8,   &Bl[(r0 + 16) * 32]);
    __syncthreads();

    short8 ah[4], al[4], bh[4], bl[4];
#pragma unroll
    for (int rt = 0; rt < 4; ++rt) {
      int ar = rb + rt * 16 + l15;
      ah[rt] = *(const short8*)&Ah[ar * 32 + q8];
      al[rt] = *(const short8*)&Al[ar * 32 + q8];
    }
#pragma unroll
    for (int ct = 0; ct < 4; ++ct) {
      int br = cb + ct * 16 + l15;
      bh[ct] = *(const short8*)&Bh[br * 32 + q8];
      bl[ct] = *(const short8*)&Bl[br * 32 + q8];
    }
#pragma unroll
    for (int rt = 0; rt < 4; ++rt)
#pragma unroll
      for (int ct = 0; ct < 4; ++ct) {
        acc[rt][ct] = __builtin_amdgcn_mfma_f32_16x16x32_bf16(ah[rt], bh[ct], acc[rt][ct], 0, 0, 0);
        acc[rt][ct] = __builtin_amdgcn_mfma_f32_16x16x32_bf16(ah[rt], bl[ct], acc[rt][ct], 0, 0, 0);
        acc[rt][ct] = __builtin_amdgcn_mfma_f32_16x16x32_bf16(al[rt], bh[ct], acc[rt][ct], 0, 0, 0);
      }
  }

  // fold: q = s - 2*m~ ; C/D layout: row = quad*4+reg, col = lane&15
  const int quad = ln >> 4;
  float sv[4];
#pragma unroll
  for (int ct = 0; ct < 4; ++ct) sv[ct] = ss[kc + cb + ct * 16 + l15];
  // pass 1: block-wide best
#pragma unroll
  for (int rt = 0; rt < 4; ++rt)
#pragma unroll
    for (int reg = 0; reg < 4; ++reg) {
      int row = rb + rt * 16 + quad * 4 + reg;
      ull b1 = ~0ull;
#pragma unroll
      for (int ct = 0; ct < 4; ++ct) {
        float q = fmaf(-2.f, acc[rt][ct][reg], sv[ct]);
        ull key = pk(q, kc + cb + ct * 16 + l15);
        if (key < b1) b1 = key;
      }
      atomicMin(&best1[row], b1);
    }
  __syncthreads();
  // pass 2: block-wide 2nd-best (winner lane submits its local 2nd)
#pragma unroll
  for (int rt = 0; rt < 4; ++rt)
#pragma unroll
    for (int reg = 0; reg < 4; ++reg) {
      int row = rb + rt * 16 + quad * 4 + reg;
      ull b1 = ~0ull, b2 = ~0ull;
#pragma unroll
      for (int ct = 0; ct < 4; ++ct) {
        float q = fmaf(-2.f, acc[rt][ct][reg], sv[ct]);
        ull key = pk(q, kc + cb + ct * 16 + l15);
        if (key < b1) { b2 = b1; b1 = key; } else if (key < b2) { b2 = key; }
      }
      atomicMin(&best2[row], (b1 == best1[row]) ? b2 : b1);
    }
  __syncthreads();
  if (t < 128) {
    gb8[(size_t)(n0 + t) * 8 + blockIdx.y] = best1[t];
    gs8[(size_t)(n0 + t) * 8 + blockIdx.y] = best2[t];
  }
}

// merge 8 codeblocks -> global best/2nd; certify gap or flag for exact fallback
__global__ void k_reduce(const ull* __restrict__ gb8, const ull* __restrict__ gs8,
                         ull* __restrict__ gbest, int* __restrict__ flags,
                         int* __restrict__ flagcnt) {
  int g = blockIdx.x * 256 + threadIdx.x;  // 32768 rows
  const ull* b = gb8 + (size_t)g * 8;
  const ull* s = gs8 + (size_t)g * 8;
  ull g1 = ~0ull; int cbw = 0;
#pragma unroll
  for (int cb = 0; cb < 8; ++cb) { ull v = b[cb]; if (v < g1) { g1 = v; cbw = cb; } }
  ull g2 = s[cbw];
#pragma unroll
  for (int cb = 0; cb < 8; ++cb) if (cb != cbw && b[cb] < g2) g2 = b[cb];
  gbest[g] = g1;
  float gap = keyq(g2) - keyq(g1);
  if (!(gap > GUARD)) { int p = atomicAdd(flagcnt, 1); flags[p] = g; }
}

// exact numpy-replicating recheck for flagged rows (sequential-fma m, pair128 r)
__global__ __launch_bounds__(256) void k_fallback(
    const float* __restrict__ in, const float* __restrict__ wT,
    const float* __restrict__ ss, const int* __restrict__ flags,
    const int* __restrict__ flagcnt, ull* __restrict__ gbest) {
  __shared__ float xrow[256];
  __shared__ float rsh;
  __shared__ ull bmin;
  const int t = threadIdx.x;
  const int cnt = *flagcnt;
  for (int i = blockIdx.x; i < cnt; i += 1024) {
    int row = flags[i];
    __syncthreads();   // previous iteration fully consumed
    int b = row >> 10, hw = row & 1023;
    xrow[t] = in[b * BSTRIDE + t * HWDIM + hw];
    if (t == 0) bmin = ~0ull;
    __syncthreads();
    if (t == 0) rsh = __fadd_rn(pair128_sq(xrow, 1), pair128_sq(xrow + 128, 1));
    __syncthreads();
    float m[4] = {0.f, 0.f, 0.f, 0.f};
    for (int d = 0; d < 256; ++d) {
      float xv = xrow[d];
      const float* wd = wT + (size_t)d * KCODES + t;
      m[0] = fmaf(xv, wd[0], m[0]);
      m[1] = fmaf(xv, wd[256], m[1]);
      m[2] = fmaf(xv, wd[512], m[2]);
      m[3] = fmaf(xv, wd[768], m[3]);
    }
    ull lb = ~0ull;
#pragma unroll
    for (int j = 0; j < 4; ++j) {
      int k = t + j * 256;
      float dist = fmaf(-2.f, m[j], __fadd_rn(rsh, ss[k]));
      ull key = pk(dist, k);
      if (key < lb) lb = key;
    }
    atomicMin(&bmin, lb);
    __syncthreads();
    if (t == 0) gbest[row] = bmin;
  }
}

// one-hot encodings write (including zeros) + histogram. 4 rows per block.
__global__ void k_enc(const ull* __restrict__ gbest,
                      float2* __restrict__ enc, int* __restrict__ hist) {
  __shared__ unsigned kk[4];
  const int t = threadIdx.x;
  const int r0 = blockIdx.x * 4;
  if (t < 4) {
    unsigned k = (unsigned)(gbest[r0 + t] & 0xFFFFFFFFull);
    kk[t] = k;
    atomicAdd(&hist[k], 1);
  }
  __syncthreads();
#pragma unroll
  for (int m = 0; m < 8; ++m) {
    int u = t + m * 256;
    int r = u >> 9, c2 = u & 511;
    int k = (int)kk[r];
    float2 v;
    v.x = (c2 * 2 == k) ? 1.0f : 0.0f;
    v.y = (c2 * 2 + 1 == k) ? 1.0f : 0.0f;
    enc[(size_t)(r0 + r) * 512 + c2] = v;
  }
}

// quantized_st + squared-error sum
__global__ __launch_bounds__(256) void k_quant(
    const float* __restrict__ in, const float* __restrict__ w,
    const ull* __restrict__ gbest,
    float* __restrict__ outq, double* __restrict__ loss) {
  __shared__ float wrow[64][65];
  __shared__ unsigned kk[64];
  __shared__ double red[256];
  const int t = threadIdx.x;
  const int n0 = blockIdx.x * 64;
  const int b = n0 >> 10, hw0 = n0 & 1023;
  const float* inb = in + b * BSTRIDE + hw0;
  float* outb = outq + b * BSTRIDE + hw0;

  if (t < 64) kk[t] = (unsigned)(gbest[n0 + t] & 0xFFFFFFFFull);

  const int hwl = t & 63, dl = t >> 6;
  double lsum = 0.0;
  for (int dc = 0; dc < DDIM; dc += 64) {
    __syncthreads();
#pragma unroll
    for (int m = 0; m < 16; ++m) {
      int u = t + m * 256;
      int r = u >> 6, dd = u & 63;
      wrow[r][dd] = w[kk[r] * DDIM + dc + dd];
    }
    __syncthreads();
#pragma unroll
    for (int dd = 0; dd < 64; dd += 4) {
      int d = dc + dd + dl;
      float x = inb[d * HWDIM + hwl];
      float wv = wrow[hwl][dd + dl];
      float diff = __fsub_rn(wv, x);
      outb[d * HWDIM + hwl] = __fadd_rn(x, diff);
      lsum += (double)diff * (double)diff;
    }
  }
  red[t] = lsum;
  __syncthreads();
  for (int s = 128; s > 0; s >>= 1) {
    if (t < s) red[t] += red[t + s];
    __syncthreads();
  }
  if (t == 0) atomicAdd(loss, red[0]);
}

__global__ void k_final(const int* __restrict__ hist, const double* __restrict__ loss,
                        float* __restrict__ out) {
  __shared__ double red[256];
  int t = threadIdx.x;
  double s = 0.0;
  for (int i = t; i < KCODES; i += 256) {
    double p = (double)hist[i] * (1.0 / 32768.0);
    s += p * log(p + 1e-10);
  }
  red[t] = s;
  __syncthreads();
  for (int st = 128; st > 0; st >>= 1) {
    if (t < st) red[t] += red[t + st];
    __syncthreads();
  }
  if (t == 0) {
    out[8388609] = (float)exp(-red[0]);
    double m = *loss / 8388608.0;
    out[0] = (float)(1.25 * m);
  }
}

extern "C" void kernel_launch(void* const* d_in, const int* in_sizes, int n_in,
                              void* d_out, int out_size, void* d_ws, size_t ws_size,
                              hipStream_t stream) {
  const float* in = (const float*)d_in[0];   // [32,256,32,32]
  const float* w  = (const float*)d_in[1];   // [1024,256]
  float* out = (float*)d_out;

  char* wsb = (char*)d_ws;
  float* wT       = (float*)(wsb + 0);
  float* ssp      = (float*)(wsb + 1048576);
  ull*   gbest    = (ull*)  (wsb + 1052672);
  int*   hist     = (int*)  (wsb + 1314816);
  int*   flags    = (int*)  (wsb + 1318912);
  int*   flagcnt  = (int*)  (wsb + 1449984);
  double* loss    = (double*)(wsb + 1449992);

  // scratch in the (not-yet-written) encodings region of d_out; 16-aligned
  char* ob = (char*)d_out + 33554448;
  unsigned short* xh8 = (unsigned short*)(ob + 0);
  unsigned short* xl8 = (unsigned short*)(ob + 16777216);
  ull* gb8            = (ull*)(ob + 33554432);
  ull* gs8            = (ull*)(ob + 35651584);
  unsigned short* wh8 = (unsigned short*)(ob + 37748736);
  unsigned short* wl8 = (unsigned short*)(ob + 38273024);

  k_prep<<<dim3(128), dim3(256), 0, stream>>>(w, ssp, hist, flagcnt, loss, wh8, wl8);
  k_transpose<<<dim3(64), dim3(256), 0, stream>>>(w, wT);
  k_split<<<dim3(512), dim3(256), 0, stream>>>(in, xh8, xl8);
  k_mfma<<<dim3(256, 8), dim3(256), 0, stream>>>(xh8, xl8, wh8, wl8, ssp, gb8, gs8);
  k_reduce<<<dim3(128), dim3(256), 0, stream>>>(gb8, gs8, gbest, flags, flagcnt);
  k_fallback<<<dim3(1024), dim3(256), 0, stream>>>(in, wT, ssp, flags, flagcnt, gbest);
  k_enc<<<dim3(8192), dim3(256), 0, stream>>>(gbest, (float2*)(out + 8388610), hist);
  k_quant<<<dim3(512), dim3(256), 0, stream>>>(in, w, gbest, out + 1, loss);
  k_final<<<dim3(1), dim3(256), 0, stream>>>(hist, loss, out);
}

// Round 6
// 430.846 us; speedup vs baseline: 1.4456x; 1.1164x over previous
//
#include <hip/hip_runtime.h>
#include <hip/hip_bf16.h>

#define HWDIM 1024             // 32*32
#define DDIM 256
#define KCODES 1024
#define NROWS 32768            // 32 * 1024
#define BSTRIDE (DDIM * HWDIM) // per-batch stride = 262144
#define GUARD 1.5e-4f          // certified gap (covers 2x dist roundings @256 + split err)

typedef __attribute__((ext_vector_type(8))) short short8;
typedef __attribute__((ext_vector_type(4))) float f32x4;
typedef unsigned long long ull;

// ---- ws byte layout ----
// wT    @0        (1048576)  fp32 codebook transposed [256][1024] (fallback)
// ss    @1048576  (4096)     ||e_k||^2 numpy-pairwise
// gbest @1052672  (262144)   packed (ordered_dist<<32|k) per row
// hist  @1314816  (4096)
// flags @1318912  (131072)   int per row: 1 = needs exact fallback
// loss  @1449984  (8)        double
// ---- scratch in d_out encodings region (overwritten later by k_encquant) ----
// ob = (char*)d_out + 33554448: wh8 @0 (524288), wl8 @524288 (524288)

__device__ __forceinline__ unsigned short f2bf(float v) {
  __hip_bfloat16 b = __float2bfloat16(v);
  return *reinterpret_cast<unsigned short*>(&b);
}
__device__ __forceinline__ float bf2f(unsigned short u) {
  __hip_bfloat16 b;
  *reinterpret_cast<unsigned short*>(&b) = u;
  return __bfloat162float(b);
}
__device__ __forceinline__ ull pk(float d, int k) {
  unsigned ub = __float_as_uint(d);
  ub = (ub & 0x80000000u) ? ~ub : (ub | 0x80000000u);  // monotone total order
  return ((ull)ub << 32) | (unsigned)k;
}
__device__ __forceinline__ float keyq(ull key) {
  unsigned ub = (unsigned)(key >> 32);
  unsigned orig = (ub & 0x80000000u) ? (ub & 0x7FFFFFFFu) : ~ub;
  return __uint_as_float(orig);
}

// numpy-exact pairwise sum of squares over 128 elements
__device__ __forceinline__ float pair128_sq(const float* p, int stride) {
  float a[8];
#pragma unroll
  for (int j = 0; j < 8; ++j) { float v = p[j * stride]; a[j] = __fmul_rn(v, v); }
  for (int i = 8; i < 128; i += 8) {
#pragma unroll
    for (int j = 0; j < 8; ++j) {
      float v = p[(i + j) * stride];
      a[j] = __fadd_rn(a[j], __fmul_rn(v, v));
    }
  }
  float s01 = __fadd_rn(a[0], a[1]), s23 = __fadd_rn(a[2], a[3]);
  float s45 = __fadd_rn(a[4], a[5]), s67 = __fadd_rn(a[6], a[7]);
  return __fadd_rn(__fadd_rn(s01, s23), __fadd_rn(s45, s67));
}

// prep: w bf16 hi/lo split [oct][k][8], wT transpose, ss, inits. grid 128.
__global__ __launch_bounds__(256) void k_prep(
    const float* __restrict__ w, float* __restrict__ wT, float* __restrict__ ss,
    int* __restrict__ hist, double* __restrict__ loss,
    unsigned short* __restrict__ wh8, unsigned short* __restrict__ wl8) {
  __shared__ float tile[64][65];
  const int t = threadIdx.x;
  int g = blockIdx.x * 256 + t;   // 32768 = 1024 k x 32 octets
  {
    int k = g >> 5, oct = g & 31;
    const float* p = w + k * DDIM + oct * 8;
    short8 hv, lv;
#pragma unroll
    for (int j = 0; j < 8; ++j) {
      float v = p[j];
      unsigned short h = f2bf(v);
      unsigned short l = f2bf(__fsub_rn(v, bf2f(h)));
      hv[j] = (short)h; lv[j] = (short)l;
    }
    *(short8*)&wh8[oct * 8192 + k * 8] = hv;
    *(short8*)&wl8[oct * 8192 + k * 8] = lv;
  }
  if (g < KCODES) {
    hist[g] = 0;
    const float* p = w + g * DDIM;
    ss[g] = __fadd_rn(pair128_sq(p, 1), pair128_sq(p + 128, 1));
  }
  if (g == 0) *loss = 0.0;
  // transpose (blocks 0..63): w[k][d] -> wT[d][k], 64x64 tiles
  if (blockIdx.x < 64) {
    const int k0 = (blockIdx.x & 15) * 64, d0 = (blockIdx.x >> 4) * 64;
    const int c = t & 63, r = t >> 6;
#pragma unroll
    for (int m = 0; m < 16; ++m)
      tile[r + m * 4][c] = w[(k0 + r + m * 4) * DDIM + d0 + c];
    __syncthreads();
#pragma unroll
    for (int m = 0; m < 16; ++m)
      wT[(size_t)(d0 + r + m * 4) * KCODES + k0 + c] = tile[c][r + m * 4];
  }
}

// single-pass MFMA argmin: block = 64 rows x ALL 1024 codes. grid 512.
// A (x rows) split to bf16 h/l in-kernel, LDS layout [oct][row][8] -> frag
// reads are 16B lane-stride (2-way, free). B frags read directly from global
// (L2-resident, 256B contiguous per quarter-wave). No barriers in K-loop.
__global__ __launch_bounds__(256) void k_argmfma(
    const float* __restrict__ in,
    const unsigned short* __restrict__ wh8, const unsigned short* __restrict__ wl8,
    const float* __restrict__ ss, ull* __restrict__ gbest, int* __restrict__ flags) {
  __shared__ __align__(16) unsigned short Ah[32 * 64 * 8];  // 32 KB
  __shared__ __align__(16) unsigned short Al[32 * 64 * 8];  // 32 KB
  __shared__ ull best1[64], best2[64];

  const int t = threadIdx.x;
  const int n0 = blockIdx.x * 64;       // 64 | 1024 -> single batch per block
  const int b = n0 >> 10, hw0 = n0 & 1023;

  // ---- in-kernel split of x rows into LDS (identical h/l formulas to R5) ----
  {
    const int hw = t & 63, dg = t >> 6;
    const float* xp = in + b * BSTRIDE + hw0 + hw;
#pragma unroll
    for (int dd = 0; dd < 64; dd += 2) {
      int d = dg * 64 + dd;
      float f0 = xp[d * HWDIM], f1 = xp[(d + 1) * HWDIM];
      unsigned short h0 = f2bf(f0);
      unsigned short l0 = f2bf(__fsub_rn(f0, bf2f(h0)));
      unsigned short h1 = f2bf(f1);
      unsigned short l1 = f2bf(__fsub_rn(f1, bf2f(h1)));
      int base = ((d >> 3) * 64 + hw) * 8 + (d & 7);   // j even -> u32 pack ok
      *(unsigned*)&Ah[base] = (unsigned)h0 | ((unsigned)h1 << 16);
      *(unsigned*)&Al[base] = (unsigned)l0 | ((unsigned)l1 << 16);
    }
  }
  if (t < 64) { best1[t] = ~0ull; best2[t] = ~0ull; }
  __syncthreads();

  const int wv = t >> 6, ln = t & 63;
  const int rw = (wv & 1) * 32;          // wave's 32-row slice
  const int cw = (wv >> 1) * 64;         // wave's 64-code column within each kb
  const int l15 = ln & 15, quad = ln >> 4;

  ull rb1[8], rb2[8];                    // running best/2nd per (rt,reg) row
#pragma unroll
  for (int i = 0; i < 8; ++i) { rb1[i] = ~0ull; rb2[i] = ~0ull; }

  for (int kb = 0; kb < 8; ++kb) {
    const int cb = kb * 128 + cw;
    f32x4 acc[2][4];
#pragma unroll
    for (int rt = 0; rt < 2; ++rt)
#pragma unroll
      for (int ct = 0; ct < 4; ++ct) acc[rt][ct] = (f32x4){0.f, 0.f, 0.f, 0.f};

#pragma unroll
    for (int ki = 0; ki < 8; ++ki) {
      const int obase = ki * 4 + quad;
      short8 ah[2], al[2], bh[4], bl[4];
#pragma unroll
      for (int rt = 0; rt < 2; ++rt) {
        int row = rw + rt * 16 + l15;
        ah[rt] = *(const short8*)&Ah[(obase * 64 + row) * 8];
        al[rt] = *(const short8*)&Al[(obase * 64 + row) * 8];
      }
#pragma unroll
      for (int ct = 0; ct < 4; ++ct) {
        int off = obase * 8192 + (cb + ct * 16 + l15) * 8;
        bh[ct] = *(const short8*)&wh8[off];
        bl[ct] = *(const short8*)&wl8[off];
      }
#pragma unroll
      for (int rt = 0; rt < 2; ++rt)
#pragma unroll
        for (int ct = 0; ct < 4; ++ct) {
          acc[rt][ct] = __builtin_amdgcn_mfma_f32_16x16x32_bf16(ah[rt], bh[ct], acc[rt][ct], 0, 0, 0);
          acc[rt][ct] = __builtin_amdgcn_mfma_f32_16x16x32_bf16(ah[rt], bl[ct], acc[rt][ct], 0, 0, 0);
          acc[rt][ct] = __builtin_amdgcn_mfma_f32_16x16x32_bf16(al[rt], bh[ct], acc[rt][ct], 0, 0, 0);
        }
    }

    // fold this kb's 64 codes into running per-row top-2 (lane-local)
    float sv[4];
#pragma unroll
    for (int ct = 0; ct < 4; ++ct) sv[ct] = ss[cb + ct * 16 + l15];
#pragma unroll
    for (int rt = 0; rt < 2; ++rt)
#pragma unroll
      for (int reg = 0; reg < 4; ++reg) {
        int idx = rt * 4 + reg;
        ull b1 = rb1[idx], b2 = rb2[idx];
#pragma unroll
        for (int ct = 0; ct < 4; ++ct) {
          float q = fmaf(-2.f, acc[rt][ct][reg], sv[ct]);
          ull key = pk(q, cb + ct * 16 + l15);
          if (key < b1) { b2 = b1; b1 = key; } else if (key < b2) { b2 = key; }
        }
        rb1[idx] = b1; rb2[idx] = b2;
      }
  }

  // two-pass block merge: global best, then global 2nd
#pragma unroll
  for (int rt = 0; rt < 2; ++rt)
#pragma unroll
    for (int reg = 0; reg < 4; ++reg)
      atomicMin(&best1[rw + rt * 16 + quad * 4 + reg], rb1[rt * 4 + reg]);
  __syncthreads();
#pragma unroll
  for (int rt = 0; rt < 2; ++rt)
#pragma unroll
    for (int reg = 0; reg < 4; ++reg) {
      int row = rw + rt * 16 + quad * 4 + reg;
      int idx = rt * 4 + reg;
      ull sub = (rb1[idx] == best1[row]) ? rb2[idx] : rb1[idx];
      atomicMin(&best2[row], sub);
    }
  __syncthreads();
  if (t < 64) {
    ull k1 = best1[t];
    gbest[n0 + t] = k1;
    flags[n0 + t] = (keyq(best2[t]) - keyq(k1) > GUARD) ? 0 : 1;
  }
}

// fused: exact fallback for flagged rows + hist + one-hot enc + quantized_st/loss
__global__ __launch_bounds__(256) void k_encquant(
    const float* __restrict__ in, const float* __restrict__ w,
    const float* __restrict__ wT, const float* __restrict__ ss,
    const ull* __restrict__ gbest, const int* __restrict__ flags,
    int* __restrict__ hist, float2* __restrict__ enc,
    float* __restrict__ outq, double* __restrict__ loss) {
  __shared__ unsigned kk[64];
  __shared__ int flist[64];
  __shared__ int nflag;
  __shared__ float xrow[256];
  __shared__ float rsh;
  __shared__ ull bmin;
  __shared__ float wrow[64][65];
  __shared__ double red[256];

  const int t = threadIdx.x;
  const int n0 = blockIdx.x * 64;      // 512 blocks
  const int b = n0 >> 10, hw0 = n0 & 1023;

  if (t == 0) nflag = 0;
  __syncthreads();
  if (t < 64) {
    kk[t] = (unsigned)(gbest[n0 + t] & 0xFFFFFFFFull);
    if (flags[n0 + t]) { int p = atomicAdd(&nflag, 1); flist[p] = t; }
  }
  __syncthreads();
  const int nf = nflag;

  // exact numpy-replicating recheck (identical op order to R5's verified path)
  for (int fi = 0; fi < nf; ++fi) {
    int r = flist[fi];
    xrow[t] = in[b * BSTRIDE + t * HWDIM + hw0 + r];
    if (t == 0) bmin = ~0ull;
    __syncthreads();
    if (t == 0) rsh = __fadd_rn(pair128_sq(xrow, 1), pair128_sq(xrow + 128, 1));
    __syncthreads();
    float m[4] = {0.f, 0.f, 0.f, 0.f};
    for (int d = 0; d < 256; ++d) {
      float xv = xrow[d];
      const float* wd = wT + (size_t)d * KCODES + t;
      m[0] = fmaf(xv, wd[0], m[0]);
      m[1] = fmaf(xv, wd[256], m[1]);
      m[2] = fmaf(xv, wd[512], m[2]);
      m[3] = fmaf(xv, wd[768], m[3]);
    }
    ull lb = ~0ull;
#pragma unroll
    for (int j = 0; j < 4; ++j) {
      int k = t + j * 256;
      float dist = fmaf(-2.f, m[j], __fadd_rn(rsh, ss[k]));
      ull key = pk(dist, k);
      if (key < lb) lb = key;
    }
    atomicMin(&bmin, lb);
    __syncthreads();
    if (t == 0) kk[r] = (unsigned)(bmin & 0xFFFFFFFFull);
    __syncthreads();
  }

  if (t < 64) atomicAdd(&hist[kk[t]], 1);
  __syncthreads();   // kk final

  // one-hot: 64 rows x 512 float2
#pragma unroll 4
  for (int m = 0; m < 128; ++m) {
    int u = m * 256 + t;
    int r = u >> 9, c2 = u & 511;
    int k = (int)kk[r];
    float2 v;
    v.x = (c2 * 2 == k) ? 1.0f : 0.0f;
    v.y = (c2 * 2 + 1 == k) ? 1.0f : 0.0f;
    enc[(size_t)(n0 + r) * 512 + c2] = v;
  }

  // quantized_st + loss
  const float* inb = in + b * BSTRIDE + hw0;
  float* outb = outq + b * BSTRIDE + hw0;
  const int hwl = t & 63, dl = t >> 6;
  double lsum = 0.0;
  for (int dc = 0; dc < DDIM; dc += 64) {
    __syncthreads();
#pragma unroll
    for (int m = 0; m < 16; ++m) {
      int u = t + m * 256;
      int r = u >> 6, dd = u & 63;
      wrow[r][dd] = w[kk[r] * DDIM + dc + dd];
    }
    __syncthreads();
#pragma unroll
    for (int dd = 0; dd < 64; dd += 4) {
      int d = dc + dd + dl;
      float x = inb[d * HWDIM + hwl];
      float wv = wrow[hwl][dd + dl];
      float diff = __fsub_rn(wv, x);               // fl(quantized - x)
      outb[d * HWDIM + hwl] = __fadd_rn(x, diff);  // fl(x + fl(q - x)) == np
      lsum += (double)diff * (double)diff;
    }
  }
  red[t] = lsum;
  __syncthreads();
  for (int s = 128; s > 0; s >>= 1) {
    if (t < s) red[t] += red[t + s];
    __syncthreads();
  }
  if (t == 0) atomicAdd(loss, red[0]);
}

__global__ void k_final(const int* __restrict__ hist, const double* __restrict__ loss,
                        float* __restrict__ out) {
  __shared__ double red[256];
  int t = threadIdx.x;
  double s = 0.0;
  for (int i = t; i < KCODES; i += 256) {
    double p = (double)hist[i] * (1.0 / 32768.0);
    s += p * log(p + 1e-10);
  }
  red[t] = s;
  __syncthreads();
  for (int st = 128; st > 0; st >>= 1) {
    if (t < st) red[t] += red[t + st];
    __syncthreads();
  }
  if (t == 0) {
    out[8388609] = (float)exp(-red[0]);
    double m = *loss / 8388608.0;
    out[0] = (float)(1.25 * m);   // q_latent + 0.25 * e_latent, identical values
  }
}

extern "C" void kernel_launch(void* const* d_in, const int* in_sizes, int n_in,
                              void* d_out, int out_size, void* d_ws, size_t ws_size,
                              hipStream_t stream) {
  const float* in = (const float*)d_in[0];   // [32,256,32,32]
  const float* w  = (const float*)d_in[1];   // [1024,256]
  float* out = (float*)d_out;

  char* wsb = (char*)d_ws;
  float* wT    = (float*)(wsb + 0);
  float* ssp   = (float*)(wsb + 1048576);
  ull*   gbest = (ull*)  (wsb + 1052672);
  int*   hist  = (int*)  (wsb + 1314816);
  int*   flags = (int*)  (wsb + 1318912);
  double* loss = (double*)(wsb + 1449984);

  // w split scratch in (not-yet-written) encodings region of d_out
  char* ob = (char*)d_out + 33554448;
  unsigned short* wh8 = (unsigned short*)(ob + 0);
  unsigned short* wl8 = (unsigned short*)(ob + 524288);

  k_prep<<<dim3(128), dim3(256), 0, stream>>>(w, wT, ssp, hist, loss, wh8, wl8);
  k_argmfma<<<dim3(512), dim3(256), 0, stream>>>(in, wh8, wl8, ssp, gbest, flags);
  k_encquant<<<dim3(512), dim3(256), 0, stream>>>(in, w, wT, ssp, gbest, flags,
                                                  hist, (float2*)(out + 8388610),
                                                  out + 1, loss);
  k_final<<<dim3(1), dim3(256), 0, stream>>>(hist, loss, out);
}